// Round 1
// baseline (2037.109 us; speedup 1.0000x reference)
//
#include <hip/hip_runtime.h>

#define NN 100000
#define NE 3200000
#define NF 512
#define NH 256
#define NL 64
#define NB_SCAN 391   // ceil(NN/256)

// ---------------- CSR build ----------------
__global__ void k_hist(const int* __restrict__ dst, int* __restrict__ deg) {
    int e = blockIdx.x * 256 + threadIdx.x;
    if (e < NE) atomicAdd(&deg[dst[e]], 1);
}

__global__ void k_blocksum(const int* __restrict__ deg, int* __restrict__ bsum) {
    __shared__ int s[256];
    int t = threadIdx.x;
    int i = blockIdx.x * 256 + t;
    s[t] = (i < NN) ? deg[i] : 0;
    __syncthreads();
    for (int off = 128; off > 0; off >>= 1) {
        if (t < off) s[t] += s[t + off];
        __syncthreads();
    }
    if (t == 0) bsum[blockIdx.x] = s[0];
}

__global__ void k_scan_partials(int* bsum) {
    // single thread: 391 elements, in-place exclusive scan
    int run = 0;
    for (int b = 0; b < NB_SCAN; b++) { int v = bsum[b]; bsum[b] = run; run += v; }
}

__global__ void k_scan_final(const int* __restrict__ deg, const int* __restrict__ boff,
                             int* __restrict__ row_ptr) {
    __shared__ int s[2][256];
    int t = threadIdx.x;
    int i = blockIdx.x * 256 + t;
    int v = (i < NN) ? deg[i] : 0;
    int buf = 0;
    s[0][t] = v;
    __syncthreads();
    for (int off = 1; off < 256; off <<= 1) {
        int nv = s[buf][t] + ((t >= off) ? s[buf][t - off] : 0);
        buf ^= 1;
        s[buf][t] = nv;
        __syncthreads();
    }
    if (i < NN) row_ptr[i] = boff[blockIdx.x] + s[buf][t] - v;  // exclusive
}

__global__ void k_scatter(const int* __restrict__ src, const int* __restrict__ dst,
                          const float* __restrict__ w, const int* __restrict__ row_ptr,
                          int* __restrict__ cursor, int* __restrict__ ssrc,
                          float* __restrict__ sw) {
    int e = blockIdx.x * 256 + threadIdx.x;
    if (e < NE) {
        int d = dst[e];
        int p = row_ptr[d] + atomicAdd(&cursor[d], 1);
        ssrc[p] = src[e];
        sw[p]   = w[e];
    }
}

// ---------------- GEMM1: XW = x @ W1   [NN,512]@[512,256] ----------------
#define G1_ROWS 16
__global__ __launch_bounds__(256) void k_gemm1(const float* __restrict__ x,
                                               const float* __restrict__ W1,
                                               float* __restrict__ XW) {
    __shared__ float4 xs[G1_ROWS][NF / 4];  // 16 rows x 512 f32 = 32 KB
    int tid = threadIdx.x;
    long nb = (long)blockIdx.x * G1_ROWS;
    for (int idx = tid; idx < G1_ROWS * (NF / 4); idx += 256) {
        int r = idx >> 7, k4 = idx & 127;
        xs[r][k4] = ((const float4*)(x + (nb + r) * NF))[k4];
    }
    __syncthreads();
    float acc[G1_ROWS];
#pragma unroll
    for (int r = 0; r < G1_ROWS; r++) acc[r] = 0.f;
    for (int k4 = 0; k4 < NF / 4; k4++) {
        float w0 = W1[(k4 * 4 + 0) * NH + tid];
        float w1 = W1[(k4 * 4 + 1) * NH + tid];
        float w2 = W1[(k4 * 4 + 2) * NH + tid];
        float w3 = W1[(k4 * 4 + 3) * NH + tid];
#pragma unroll
        for (int r = 0; r < G1_ROWS; r++) {
            float4 xv = xs[r][k4];
            acc[r] += xv.x * w0 + xv.y * w1 + xv.z * w2 + xv.w * w3;
        }
    }
#pragma unroll
    for (int r = 0; r < G1_ROWS; r++) XW[(nb + r) * NH + tid] = acc[r];
}

// ---------------- SpMM1 + bias + relu: h = relu(adj @ XW + b1) ----------------
__global__ __launch_bounds__(256) void k_spmm1(const float* __restrict__ XW,
                                               const int* __restrict__ ssrc,
                                               const float* __restrict__ sw,
                                               const int* __restrict__ row_ptr,
                                               const int* __restrict__ deg,
                                               const float* __restrict__ b1,
                                               float* __restrict__ h) {
    int wave = threadIdx.x >> 6, lane = threadIdx.x & 63;
    int n = blockIdx.x * 4 + wave;
    if (n >= NN) return;
    int start = row_ptr[n];
    int cnt = deg[n];
    float4 acc = {0.f, 0.f, 0.f, 0.f};
    const float4* base = (const float4*)XW;  // row stride 64 float4
    for (int i = 0; i < cnt; i++) {
        int s = ssrc[start + i];
        float w = sw[start + i];
        float4 v = base[(long)s * 64 + lane];
        acc.x += w * v.x; acc.y += w * v.y; acc.z += w * v.z; acc.w += w * v.w;
    }
    float4 b = ((const float4*)b1)[lane];
    float4 o;
    o.x = fmaxf(acc.x + b.x, 0.f);
    o.y = fmaxf(acc.y + b.y, 0.f);
    o.z = fmaxf(acc.z + b.z, 0.f);
    o.w = fmaxf(acc.w + b.w, 0.f);
    ((float4*)h)[(long)n * 64 + lane] = o;
}

// ---------------- GEMM2: HMHL = h @ [W_mu | W_logvar]   [NN,256]@[256,128] ----------------
#define G2_ROWS 16
__global__ __launch_bounds__(256) void k_gemm2(const float* __restrict__ h,
                                               const float* __restrict__ Wmu,
                                               const float* __restrict__ Wlv,
                                               float* __restrict__ HM) {
    __shared__ float4 hs[G2_ROWS][NH / 4];  // 16 x 256 f32 = 16 KB
    int tid = threadIdx.x;
    int col = tid & 127;   // 0..127
    int rg  = tid >> 7;    // 0..1
    long nb = (long)blockIdx.x * G2_ROWS;
    for (int idx = tid; idx < G2_ROWS * (NH / 4); idx += 256) {
        int r = idx >> 6, k4 = idx & 63;
        hs[r][k4] = ((const float4*)(h + (nb + r) * NH))[k4];
    }
    __syncthreads();
    const float* Wsel = (col < NL) ? (Wmu + col) : (Wlv + (col - NL));
    float acc[8];
#pragma unroll
    for (int r = 0; r < 8; r++) acc[r] = 0.f;
    for (int k4 = 0; k4 < NH / 4; k4++) {
        float w0 = Wsel[(k4 * 4 + 0) * NL];
        float w1 = Wsel[(k4 * 4 + 1) * NL];
        float w2 = Wsel[(k4 * 4 + 2) * NL];
        float w3 = Wsel[(k4 * 4 + 3) * NL];
#pragma unroll
        for (int r = 0; r < 8; r++) {
            float4 hv = hs[rg * 8 + r][k4];
            acc[r] += hv.x * w0 + hv.y * w1 + hv.z * w2 + hv.w * w3;
        }
    }
#pragma unroll
    for (int r = 0; r < 8; r++) HM[(nb + rg * 8 + r) * 128 + col] = acc[r];
}

// ---------------- SpMM2 + bias: out = [adj@HM + b_mu ; adj@HL + b_lv] ----------------
__global__ __launch_bounds__(256) void k_spmm2(const float* __restrict__ HM,
                                               const int* __restrict__ ssrc,
                                               const float* __restrict__ sw,
                                               const int* __restrict__ row_ptr,
                                               const int* __restrict__ deg,
                                               const float* __restrict__ bmu,
                                               const float* __restrict__ blv,
                                               float* __restrict__ out) {
    int wave = threadIdx.x >> 6, lane = threadIdx.x & 63;
    int n = blockIdx.x * 4 + wave;
    if (n >= NN) return;
    int start = row_ptr[n];
    int cnt = deg[n];
    float2 acc = {0.f, 0.f};
    const float2* base = (const float2*)HM;  // row stride 64 float2 (128 f32)
    for (int i = 0; i < cnt; i++) {
        int s = ssrc[start + i];
        float w = sw[start + i];
        float2 v = base[(long)s * 64 + lane];
        acc.x += w * v.x; acc.y += w * v.y;
    }
    if (lane < 32) {  // cols 0..63 -> mu
        float2 b = ((const float2*)bmu)[lane];
        float2 o = {acc.x + b.x, acc.y + b.y};
        ((float2*)out)[(long)n * 32 + lane] = o;
    } else {          // cols 64..127 -> logvar
        float2 b = ((const float2*)blv)[lane - 32];
        float2 o = {acc.x + b.x, acc.y + b.y};
        ((float2*)(out + (long)NN * NL))[(long)n * 32 + (lane - 32)] = o;
    }
}

extern "C" void kernel_launch(void* const* d_in, const int* in_sizes, int n_in,
                              void* d_out, int out_size, void* d_ws, size_t ws_size,
                              hipStream_t stream) {
    const float* x   = (const float*)d_in[0];
    const int*   ei  = (const int*)d_in[1];
    const float* ew  = (const float*)d_in[2];
    const float* W1  = (const float*)d_in[3];
    const float* b1  = (const float*)d_in[4];
    const float* Wmu = (const float*)d_in[5];
    const float* bmu = (const float*)d_in[6];
    const float* Wlv = (const float*)d_in[7];
    const float* blv = (const float*)d_in[8];
    float* out = (float*)d_out;

    char* ws = (char*)d_ws;
    float* XW      = (float*)(ws);                  // NN*256 f32 (102.4 MB), reused as HMHL (NN*128)
    float* h       = (float*)(ws + 102400000);      // NN*256 f32 (102.4 MB)
    int*   ssrc    = (int*)  (ws + 204800000);      // NE (12.8 MB)
    float* sw      = (float*)(ws + 217600000);      // NE (12.8 MB)
    int*   deg     = (int*)  (ws + 230400000);      // NN
    int*   row_ptr = (int*)  (ws + 230800000);      // NN
    int*   cursor  = (int*)  (ws + 231200000);      // NN
    int*   bsum    = (int*)  (ws + 231600000);      // NB_SCAN

    const int* esrc = ei;
    const int* edst = ei + NE;

    hipMemsetAsync(deg, 0, NN * sizeof(int), stream);
    hipMemsetAsync(cursor, 0, NN * sizeof(int), stream);

    // CSR build (sorted-by-dst edge list)
    k_hist<<<dim3((NE + 255) / 256), dim3(256), 0, stream>>>(edst, deg);
    k_blocksum<<<dim3(NB_SCAN), dim3(256), 0, stream>>>(deg, bsum);
    k_scan_partials<<<dim3(1), dim3(1), 0, stream>>>(bsum);
    k_scan_final<<<dim3(NB_SCAN), dim3(256), 0, stream>>>(deg, bsum, row_ptr);
    k_scatter<<<dim3((NE + 255) / 256), dim3(256), 0, stream>>>(esrc, edst, ew, row_ptr,
                                                                cursor, ssrc, sw);

    // layer 1
    k_gemm1<<<dim3(NN / G1_ROWS), dim3(256), 0, stream>>>(x, W1, XW);
    k_spmm1<<<dim3(NN / 4), dim3(256), 0, stream>>>(XW, ssrc, sw, row_ptr, deg, b1, h);

    // layer 2 (mu and logvar fused: 128-wide)
    k_gemm2<<<dim3(NN / G2_ROWS), dim3(256), 0, stream>>>(h, Wmu, Wlv, XW /* HMHL */);
    k_spmm2<<<dim3(NN / 4), dim3(256), 0, stream>>>(XW, ssrc, sw, row_ptr, deg, bmu, blv, out);
}

// Round 2
// 1480.269 us; speedup vs baseline: 1.3762x; 1.3762x over previous
//
#include <hip/hip_runtime.h>
#include <hip/hip_bf16.h>

#define NN 100000
#define NE 3200000
#define NF 512
#define NH 256
#define NL 64
#define NB_SCAN 391   // ceil(NN/256)
#define PAD 40        // LDS row stride in bf16 elems (80 B = 16B-aligned, 2-way bank alias only)

typedef __bf16 bf16x8 __attribute__((ext_vector_type(8)));
typedef float  f32x4  __attribute__((ext_vector_type(4)));

// ---------------- CSR build ----------------
__global__ void k_hist(const int* __restrict__ dst, int* __restrict__ deg) {
    int e = blockIdx.x * 256 + threadIdx.x;
    if (e < NE) atomicAdd(&deg[dst[e]], 1);
}

__global__ void k_blocksum(const int* __restrict__ deg, int* __restrict__ bsum) {
    __shared__ int s[256];
    int t = threadIdx.x;
    int i = blockIdx.x * 256 + t;
    s[t] = (i < NN) ? deg[i] : 0;
    __syncthreads();
    for (int off = 128; off > 0; off >>= 1) {
        if (t < off) s[t] += s[t + off];
        __syncthreads();
    }
    if (t == 0) bsum[blockIdx.x] = s[0];
}

// parallel exclusive scan of NB_SCAN partials, one block of 512 threads
__global__ void k_scan_partials(int* bsum) {
    __shared__ int s[512];
    int t = threadIdx.x;
    int v = (t < NB_SCAN) ? bsum[t] : 0;
    s[t] = v;
    __syncthreads();
    for (int off = 1; off < 512; off <<= 1) {
        int a = (t >= off) ? s[t - off] : 0;
        __syncthreads();
        s[t] += a;
        __syncthreads();
    }
    if (t < NB_SCAN) bsum[t] = s[t] - v;  // exclusive
}

__global__ void k_scan_final(const int* __restrict__ deg, const int* __restrict__ boff,
                             int* __restrict__ row_ptr) {
    __shared__ int s[2][256];
    int t = threadIdx.x;
    int i = blockIdx.x * 256 + t;
    int v = (i < NN) ? deg[i] : 0;
    int buf = 0;
    s[0][t] = v;
    __syncthreads();
    for (int off = 1; off < 256; off <<= 1) {
        int nv = s[buf][t] + ((t >= off) ? s[buf][t - off] : 0);
        buf ^= 1;
        s[buf][t] = nv;
        __syncthreads();
    }
    if (i < NN) row_ptr[i] = boff[blockIdx.x] + s[buf][t] - v;  // exclusive
}

__global__ void k_scatter(const int* __restrict__ src, const int* __restrict__ dst,
                          const float* __restrict__ w, const int* __restrict__ row_ptr,
                          int* __restrict__ cursor, int* __restrict__ ssrc,
                          float* __restrict__ sw) {
    int e = blockIdx.x * 256 + threadIdx.x;
    if (e < NE) {
        int d = dst[e];
        int p = row_ptr[d] + atomicAdd(&cursor[d], 1);
        ssrc[p] = src[e];
        sw[p]   = w[e];
    }
}

// ---------------- weight packing into MFMA B-fragment order ----------------
// frag element: B[k = kc*32 + (lane>>4)*8 + j][n = nt*16 + (lane&15)]
// linear index: ((nt*KC16 + kc)*64 + lane)*8 + j
__global__ void k_packW1(const float* __restrict__ W, __bf16* __restrict__ P) {
    int i = blockIdx.x * 256 + threadIdx.x;       // 131072 = 16nt * 16kc * 64 * 8
    int j = i & 7, l = (i >> 3) & 63, kc = (i >> 9) & 15, nt = i >> 13;
    int k = kc * 32 + (l >> 4) * 8 + j;
    int n = nt * 16 + (l & 15);
    P[i] = (__bf16)W[k * NH + n];
}

__global__ void k_packW2(const float* __restrict__ Wmu, const float* __restrict__ Wlv,
                         __bf16* __restrict__ P) {
    int i = blockIdx.x * 256 + threadIdx.x;       // 32768 = 8nt * 8kc * 64 * 8
    int j = i & 7, l = (i >> 3) & 63, kc = (i >> 9) & 7, nt = i >> 12;
    int k = kc * 32 + (l >> 4) * 8 + j;
    int n = nt * 16 + (l & 15);
    float v = (n < NL) ? Wmu[k * NL + n] : Wlv[k * NL + (n - NL)];
    P[i] = (__bf16)v;
}

// ---------------- GEMM1 (MFMA): XW = x @ W1   [NN,512]@[512,256] ----------------
// BM=64, BN=256, BK=32. 4 waves, wave w -> cols [w*64, w*64+64). fp32 out.
__global__ __launch_bounds__(256) void k_gemm1(const float* __restrict__ x,
                                               const __bf16* __restrict__ Wp,
                                               float* __restrict__ XW) {
    __shared__ __bf16 As[64 * PAD];
    int tid = threadIdx.x;
    int wv = tid >> 6, lane = tid & 63;
    int quad = lane >> 4, l16 = lane & 15;
    long m0 = (long)blockIdx.x * 64;

    int srow = tid >> 2;            // 0..63
    int scol = (tid & 3) * 8;       // 0,8,16,24
    long grow = m0 + srow; if (grow > NN - 1) grow = NN - 1;
    const float* xrow = x + grow * NF;

    f32x4 acc[4][4];
#pragma unroll
    for (int a = 0; a < 4; a++)
#pragma unroll
        for (int b = 0; b < 4; b++) acc[a][b] = (f32x4)0.f;

    float4 p0 = *(const float4*)(xrow + scol);
    float4 p1 = *(const float4*)(xrow + scol + 4);

    for (int kc = 0; kc < 16; kc++) {
        union { bf16x8 v; __bf16 e[8]; } u;
        u.e[0] = (__bf16)p0.x; u.e[1] = (__bf16)p0.y;
        u.e[2] = (__bf16)p0.z; u.e[3] = (__bf16)p0.w;
        u.e[4] = (__bf16)p1.x; u.e[5] = (__bf16)p1.y;
        u.e[6] = (__bf16)p1.z; u.e[7] = (__bf16)p1.w;
        *(bf16x8*)&As[srow * PAD + scol] = u.v;
        __syncthreads();
        if (kc < 15) {
            p0 = *(const float4*)(xrow + (kc + 1) * 32 + scol);
            p1 = *(const float4*)(xrow + (kc + 1) * 32 + scol + 4);
        }
        bf16x8 bfr[4];
#pragma unroll
        for (int nt = 0; nt < 4; nt++)
            bfr[nt] = *(const bf16x8*)(Wp + (((long)(wv * 4 + nt) * 16 + kc) * 64 + lane) * 8);
#pragma unroll
        for (int mt = 0; mt < 4; mt++) {
            bf16x8 af = *(const bf16x8*)&As[(mt * 16 + l16) * PAD + quad * 8];
#pragma unroll
            for (int nt = 0; nt < 4; nt++)
                acc[mt][nt] = __builtin_amdgcn_mfma_f32_16x16x32_bf16(af, bfr[nt], acc[mt][nt], 0, 0, 0);
        }
        __syncthreads();
    }
#pragma unroll
    for (int mt = 0; mt < 4; mt++)
#pragma unroll
        for (int r = 0; r < 4; r++) {
            long gr = m0 + mt * 16 + quad * 4 + r;
            if (gr < NN) {
#pragma unroll
                for (int nt = 0; nt < 4; nt++)
                    XW[gr * NH + wv * 64 + nt * 16 + l16] = acc[mt][nt][r];
            }
        }
}

// ---------------- SpMM1 + bias + relu: h = relu(adj @ XW + b1) ----------------
__global__ __launch_bounds__(256) void k_spmm1(const float* __restrict__ XW,
                                               const int* __restrict__ ssrc,
                                               const float* __restrict__ sw,
                                               const int* __restrict__ row_ptr,
                                               const int* __restrict__ deg,
                                               const float* __restrict__ b1,
                                               float* __restrict__ h) {
    int wave = threadIdx.x >> 6, lane = threadIdx.x & 63;
    int n = blockIdx.x * 4 + wave;
    if (n >= NN) return;
    int start = row_ptr[n];
    int cnt = deg[n];
    float4 acc = {0.f, 0.f, 0.f, 0.f};
    const float4* base = (const float4*)XW;  // row stride 64 float4
    for (int i = 0; i < cnt; i++) {
        int s = ssrc[start + i];
        float w = sw[start + i];
        float4 v = base[(long)s * 64 + lane];
        acc.x += w * v.x; acc.y += w * v.y; acc.z += w * v.z; acc.w += w * v.w;
    }
    float4 b = ((const float4*)b1)[lane];
    float4 o;
    o.x = fmaxf(acc.x + b.x, 0.f);
    o.y = fmaxf(acc.y + b.y, 0.f);
    o.z = fmaxf(acc.z + b.z, 0.f);
    o.w = fmaxf(acc.w + b.w, 0.f);
    ((float4*)h)[(long)n * 64 + lane] = o;
}

// ---------------- GEMM2 (MFMA): HM = h @ [W_mu|W_lv]   [NN,256]@[256,128] ----------------
// BM=128, BN=128, BK=32. 4 waves in 2x2: wave -> rows (wv>>1)*64, cols (wv&1)*64.
__global__ __launch_bounds__(256) void k_gemm2(const float* __restrict__ h,
                                               const __bf16* __restrict__ Wp,
                                               float* __restrict__ HM) {
    __shared__ __bf16 As[128 * PAD];
    int tid = threadIdx.x;
    int wv = tid >> 6, lane = tid & 63;
    int quad = lane >> 4, l16 = lane & 15;
    int wr = (wv >> 1) * 64, wc = (wv & 1) * 64;
    long m0 = (long)blockIdx.x * 128;

    int srow = tid >> 1;            // 0..127
    int scol = (tid & 1) * 16;      // 0,16
    long grow = m0 + srow; if (grow > NN - 1) grow = NN - 1;
    const float* hrow = h + grow * NH;

    f32x4 acc[4][4];
#pragma unroll
    for (int a = 0; a < 4; a++)
#pragma unroll
        for (int b = 0; b < 4; b++) acc[a][b] = (f32x4)0.f;

    float4 p0 = *(const float4*)(hrow + scol);
    float4 p1 = *(const float4*)(hrow + scol + 4);
    float4 p2 = *(const float4*)(hrow + scol + 8);
    float4 p3 = *(const float4*)(hrow + scol + 12);

    for (int kc = 0; kc < 8; kc++) {
        union { bf16x8 v; __bf16 e[8]; } u0, u1;
        u0.e[0] = (__bf16)p0.x; u0.e[1] = (__bf16)p0.y;
        u0.e[2] = (__bf16)p0.z; u0.e[3] = (__bf16)p0.w;
        u0.e[4] = (__bf16)p1.x; u0.e[5] = (__bf16)p1.y;
        u0.e[6] = (__bf16)p1.z; u0.e[7] = (__bf16)p1.w;
        u1.e[0] = (__bf16)p2.x; u1.e[1] = (__bf16)p2.y;
        u1.e[2] = (__bf16)p2.z; u1.e[3] = (__bf16)p2.w;
        u1.e[4] = (__bf16)p3.x; u1.e[5] = (__bf16)p3.y;
        u1.e[6] = (__bf16)p3.z; u1.e[7] = (__bf16)p3.w;
        *(bf16x8*)&As[srow * PAD + scol] = u0.v;
        *(bf16x8*)&As[srow * PAD + scol + 8] = u1.v;
        __syncthreads();
        if (kc < 7) {
            p0 = *(const float4*)(hrow + (kc + 1) * 32 + scol);
            p1 = *(const float4*)(hrow + (kc + 1) * 32 + scol + 4);
            p2 = *(const float4*)(hrow + (kc + 1) * 32 + scol + 8);
            p3 = *(const float4*)(hrow + (kc + 1) * 32 + scol + 12);
        }
        bf16x8 bfr[4];
#pragma unroll
        for (int nt = 0; nt < 4; nt++) {
            int ntg = (wc >> 4) + nt;   // wc/16 + nt
            bfr[nt] = *(const bf16x8*)(Wp + (((long)ntg * 8 + kc) * 64 + lane) * 8);
        }
#pragma unroll
        for (int mt = 0; mt < 4; mt++) {
            bf16x8 af = *(const bf16x8*)&As[(wr + mt * 16 + l16) * PAD + quad * 8];
#pragma unroll
            for (int nt = 0; nt < 4; nt++)
                acc[mt][nt] = __builtin_amdgcn_mfma_f32_16x16x32_bf16(af, bfr[nt], acc[mt][nt], 0, 0, 0);
        }
        __syncthreads();
    }
#pragma unroll
    for (int mt = 0; mt < 4; mt++)
#pragma unroll
        for (int r = 0; r < 4; r++) {
            long gr = m0 + wr + mt * 16 + quad * 4 + r;
            if (gr < NN) {
#pragma unroll
                for (int nt = 0; nt < 4; nt++)
                    HM[gr * 128 + wc + nt * 16 + l16] = acc[mt][nt][r];
            }
        }
}

// ---------------- SpMM2 + bias: out = [adj@HM + b_mu ; adj@HL + b_lv] ----------------
__global__ __launch_bounds__(256) void k_spmm2(const float* __restrict__ HM,
                                               const int* __restrict__ ssrc,
                                               const float* __restrict__ sw,
                                               const int* __restrict__ row_ptr,
                                               const int* __restrict__ deg,
                                               const float* __restrict__ bmu,
                                               const float* __restrict__ blv,
                                               float* __restrict__ out) {
    int wave = threadIdx.x >> 6, lane = threadIdx.x & 63;
    int n = blockIdx.x * 4 + wave;
    if (n >= NN) return;
    int start = row_ptr[n];
    int cnt = deg[n];
    float2 acc = {0.f, 0.f};
    const float2* base = (const float2*)HM;  // row stride 64 float2 (128 f32)
    for (int i = 0; i < cnt; i++) {
        int s = ssrc[start + i];
        float w = sw[start + i];
        float2 v = base[(long)s * 64 + lane];
        acc.x += w * v.x; acc.y += w * v.y;
    }
    if (lane < 32) {  // cols 0..63 -> mu
        float2 b = ((const float2*)bmu)[lane];
        float2 o = {acc.x + b.x, acc.y + b.y};
        ((float2*)out)[(long)n * 32 + lane] = o;
    } else {          // cols 64..127 -> logvar
        float2 b = ((const float2*)blv)[lane - 32];
        float2 o = {acc.x + b.x, acc.y + b.y};
        ((float2*)(out + (long)NN * NL))[(long)n * 32 + (lane - 32)] = o;
    }
}

extern "C" void kernel_launch(void* const* d_in, const int* in_sizes, int n_in,
                              void* d_out, int out_size, void* d_ws, size_t ws_size,
                              hipStream_t stream) {
    const float* x   = (const float*)d_in[0];
    const int*   ei  = (const int*)d_in[1];
    const float* ew  = (const float*)d_in[2];
    const float* W1  = (const float*)d_in[3];
    const float* b1  = (const float*)d_in[4];
    const float* Wmu = (const float*)d_in[5];
    const float* bmu = (const float*)d_in[6];
    const float* Wlv = (const float*)d_in[7];
    const float* blv = (const float*)d_in[8];
    float* out = (float*)d_out;

    char* ws = (char*)d_ws;
    float* XW      = (float*)(ws);                  // NN*256 f32 (102.4 MB), reused as HM (NN*128)
    float* h       = (float*)(ws + 102400000);      // NN*256 f32 (102.4 MB)
    int*   ssrc    = (int*)  (ws + 204800000);      // NE (12.8 MB)
    float* sw      = (float*)(ws + 217600000);      // NE (12.8 MB)
    int*   deg     = (int*)  (ws + 230400000);      // NN
    int*   row_ptr = (int*)  (ws + 230800000);      // NN
    int*   cursor  = (int*)  (ws + 231200000);      // NN
    int*   bsum    = (int*)  (ws + 231600000);      // NB_SCAN
    __bf16* Wp1    = (__bf16*)(ws + 231700000);     // 131072 bf16 (256 KB)
    __bf16* Wp2    = (__bf16*)(ws + 231962144);     // 32768 bf16 (64 KB)

    const int* esrc = ei;
    const int* edst = ei + NE;

    hipMemsetAsync(deg, 0, NN * sizeof(int), stream);
    hipMemsetAsync(cursor, 0, NN * sizeof(int), stream);

    // weight packing (L2-resident frag-order bf16)
    k_packW1<<<dim3(512), dim3(256), 0, stream>>>(W1, Wp1);
    k_packW2<<<dim3(128), dim3(256), 0, stream>>>(Wmu, Wlv, Wp2);

    // CSR build (sorted-by-dst edge list)
    k_hist<<<dim3((NE + 255) / 256), dim3(256), 0, stream>>>(edst, deg);
    k_blocksum<<<dim3(NB_SCAN), dim3(256), 0, stream>>>(deg, bsum);
    k_scan_partials<<<dim3(1), dim3(512), 0, stream>>>(bsum);
    k_scan_final<<<dim3(NB_SCAN), dim3(256), 0, stream>>>(deg, bsum, row_ptr);
    k_scatter<<<dim3((NE + 255) / 256), dim3(256), 0, stream>>>(esrc, edst, ew, row_ptr,
                                                                cursor, ssrc, sw);

    // layer 1
    k_gemm1<<<dim3((NN + 63) / 64), dim3(256), 0, stream>>>(x, Wp1, XW);
    k_spmm1<<<dim3((NN + 3) / 4), dim3(256), 0, stream>>>(XW, ssrc, sw, row_ptr, deg, b1, h);

    // layer 2 (mu and logvar fused: 128-wide)
    k_gemm2<<<dim3((NN + 127) / 128), dim3(256), 0, stream>>>(h, Wp2, XW /* HM */);
    k_spmm2<<<dim3((NN + 3) / 4), dim3(256), 0, stream>>>(XW, ssrc, sw, row_ptr, deg, bmu, blv, out);
}

// Round 3
// 1056.484 us; speedup vs baseline: 1.9282x; 1.4011x over previous
//
#include <hip/hip_runtime.h>
#include <hip/hip_bf16.h>

#define NN 100000
#define NE 3200000
#define NF 512
#define NH 256
#define NL 64
#define NB_SCAN 391   // ceil(NN/256)
#define PAD 40        // LDS row stride in bf16 elems (80 B = 16B-aligned)

typedef __bf16 bf16x8 __attribute__((ext_vector_type(8)));
typedef __bf16 bf16x4 __attribute__((ext_vector_type(4)));
typedef __bf16 bf16x2 __attribute__((ext_vector_type(2)));
typedef float  f32x4  __attribute__((ext_vector_type(4)));

// ---------------- CSR build ----------------
__global__ void k_hist(const int* __restrict__ dst, int* __restrict__ deg) {
    int e = blockIdx.x * 256 + threadIdx.x;
    if (e < NE) atomicAdd(&deg[dst[e]], 1);
}

__global__ void k_blocksum(const int* __restrict__ deg, int* __restrict__ bsum) {
    __shared__ int s[256];
    int t = threadIdx.x;
    int i = blockIdx.x * 256 + t;
    s[t] = (i < NN) ? deg[i] : 0;
    __syncthreads();
    for (int off = 128; off > 0; off >>= 1) {
        if (t < off) s[t] += s[t + off];
        __syncthreads();
    }
    if (t == 0) bsum[blockIdx.x] = s[0];
}

__global__ void k_scan_partials(int* bsum) {
    __shared__ int s[512];
    int t = threadIdx.x;
    int v = (t < NB_SCAN) ? bsum[t] : 0;
    s[t] = v;
    __syncthreads();
    for (int off = 1; off < 512; off <<= 1) {
        int a = (t >= off) ? s[t - off] : 0;
        __syncthreads();
        s[t] += a;
        __syncthreads();
    }
    if (t < NB_SCAN) bsum[t] = s[t] - v;  // exclusive
}

__global__ void k_scan_final(const int* __restrict__ deg, const int* __restrict__ boff,
                             int* __restrict__ row_ptr) {
    __shared__ int s[2][256];
    int t = threadIdx.x;
    int i = blockIdx.x * 256 + t;
    int v = (i < NN) ? deg[i] : 0;
    int buf = 0;
    s[0][t] = v;
    __syncthreads();
    for (int off = 1; off < 256; off <<= 1) {
        int nv = s[buf][t] + ((t >= off) ? s[buf][t - off] : 0);
        buf ^= 1;
        s[buf][t] = nv;
        __syncthreads();
    }
    if (i < NN) row_ptr[i] = boff[blockIdx.x] + s[buf][t] - v;  // exclusive
}

__global__ void k_scatter(const int* __restrict__ src, const int* __restrict__ dst,
                          const float* __restrict__ w, const int* __restrict__ row_ptr,
                          int* __restrict__ cursor, int* __restrict__ ssrc,
                          float* __restrict__ sw) {
    int e = blockIdx.x * 256 + threadIdx.x;
    if (e < NE) {
        int d = dst[e];
        int p = row_ptr[d] + atomicAdd(&cursor[d], 1);
        ssrc[p] = src[e];
        sw[p]   = w[e];
    }
}

// ---------------- weight packing into MFMA B-fragment order ----------------
__global__ void k_packW1(const float* __restrict__ W, __bf16* __restrict__ P) {
    int i = blockIdx.x * 256 + threadIdx.x;       // 131072 = 16nt * 16kc * 64 * 8
    int j = i & 7, l = (i >> 3) & 63, kc = (i >> 9) & 15, nt = i >> 13;
    int k = kc * 32 + (l >> 4) * 8 + j;
    int n = nt * 16 + (l & 15);
    P[i] = (__bf16)W[k * NH + n];
}

__global__ void k_packW2(const float* __restrict__ Wmu, const float* __restrict__ Wlv,
                         __bf16* __restrict__ P) {
    int i = blockIdx.x * 256 + threadIdx.x;       // 32768 = 8nt * 8kc * 64 * 8
    int j = i & 7, l = (i >> 3) & 63, kc = (i >> 9) & 7, nt = i >> 12;
    int k = kc * 32 + (l >> 4) * 8 + j;
    int n = nt * 16 + (l & 15);
    float v = (n < NL) ? Wmu[k * NL + n] : Wlv[k * NL + (n - NL)];
    P[i] = (__bf16)v;
}

// ---------------- GEMM1 (MFMA): XWb = bf16(x @ W1)   [NN,512]@[512,256] ----------------
__global__ __launch_bounds__(256) void k_gemm1(const float* __restrict__ x,
                                               const __bf16* __restrict__ Wp,
                                               __bf16* __restrict__ XWb) {
    __shared__ __bf16 As[64 * PAD];
    int tid = threadIdx.x;
    int wv = tid >> 6, lane = tid & 63;
    int quad = lane >> 4, l16 = lane & 15;
    long m0 = (long)blockIdx.x * 64;

    int srow = tid >> 2;            // 0..63
    int scol = (tid & 3) * 8;       // 0,8,16,24
    long grow = m0 + srow; if (grow > NN - 1) grow = NN - 1;
    const float* xrow = x + grow * NF;

    f32x4 acc[4][4];
#pragma unroll
    for (int a = 0; a < 4; a++)
#pragma unroll
        for (int b = 0; b < 4; b++) acc[a][b] = (f32x4)0.f;

    float4 p0 = *(const float4*)(xrow + scol);
    float4 p1 = *(const float4*)(xrow + scol + 4);

    for (int kc = 0; kc < 16; kc++) {
        union { bf16x8 v; __bf16 e[8]; } u;
        u.e[0] = (__bf16)p0.x; u.e[1] = (__bf16)p0.y;
        u.e[2] = (__bf16)p0.z; u.e[3] = (__bf16)p0.w;
        u.e[4] = (__bf16)p1.x; u.e[5] = (__bf16)p1.y;
        u.e[6] = (__bf16)p1.z; u.e[7] = (__bf16)p1.w;
        *(bf16x8*)&As[srow * PAD + scol] = u.v;
        __syncthreads();
        if (kc < 15) {
            p0 = *(const float4*)(xrow + (kc + 1) * 32 + scol);
            p1 = *(const float4*)(xrow + (kc + 1) * 32 + scol + 4);
        }
        bf16x8 bfr[4];
#pragma unroll
        for (int nt = 0; nt < 4; nt++)
            bfr[nt] = *(const bf16x8*)(Wp + (((long)(wv * 4 + nt) * 16 + kc) * 64 + lane) * 8);
#pragma unroll
        for (int mt = 0; mt < 4; mt++) {
            bf16x8 af = *(const bf16x8*)&As[(mt * 16 + l16) * PAD + quad * 8];
#pragma unroll
            for (int nt = 0; nt < 4; nt++)
                acc[mt][nt] = __builtin_amdgcn_mfma_f32_16x16x32_bf16(af, bfr[nt], acc[mt][nt], 0, 0, 0);
        }
        __syncthreads();
    }
#pragma unroll
    for (int mt = 0; mt < 4; mt++)
#pragma unroll
        for (int r = 0; r < 4; r++) {
            long gr = m0 + mt * 16 + quad * 4 + r;
            if (gr < NN) {
#pragma unroll
                for (int nt = 0; nt < 4; nt++)
                    XWb[gr * NH + wv * 64 + nt * 16 + l16] = (__bf16)acc[mt][nt][r];
            }
        }
}

// ---------------- SpMM1 + bias + relu: hb = bf16(relu(adj @ XWb + b1)) ----------------
__global__ __launch_bounds__(256) void k_spmm1(const __bf16* __restrict__ XWb,
                                               const int* __restrict__ ssrc,
                                               const float* __restrict__ sw,
                                               const int* __restrict__ row_ptr,
                                               const int* __restrict__ deg,
                                               const float* __restrict__ b1,
                                               __bf16* __restrict__ hb) {
    int wave = threadIdx.x >> 6, lane = threadIdx.x & 63;
    int n = blockIdx.x * 4 + wave;
    if (n >= NN) return;
    int i = row_ptr[n];
    int end = i + deg[n];
    float a0 = 0.f, a1 = 0.f, a2 = 0.f, a3 = 0.f;
    const bf16x4* base = (const bf16x4*)XWb;  // row stride 64 bf16x4
    for (; i + 4 <= end; i += 4) {
        int s0 = ssrc[i], s1 = ssrc[i + 1], s2 = ssrc[i + 2], s3 = ssrc[i + 3];
        float w0 = sw[i], w1 = sw[i + 1], w2 = sw[i + 2], w3 = sw[i + 3];
        bf16x4 v0 = base[(long)s0 * 64 + lane];
        bf16x4 v1 = base[(long)s1 * 64 + lane];
        bf16x4 v2 = base[(long)s2 * 64 + lane];
        bf16x4 v3 = base[(long)s3 * 64 + lane];
        a0 += w0 * (float)v0[0] + w1 * (float)v1[0] + w2 * (float)v2[0] + w3 * (float)v3[0];
        a1 += w0 * (float)v0[1] + w1 * (float)v1[1] + w2 * (float)v2[1] + w3 * (float)v3[1];
        a2 += w0 * (float)v0[2] + w1 * (float)v1[2] + w2 * (float)v2[2] + w3 * (float)v3[2];
        a3 += w0 * (float)v0[3] + w1 * (float)v1[3] + w2 * (float)v2[3] + w3 * (float)v3[3];
    }
    for (; i < end; i++) {
        int s = ssrc[i];
        float w = sw[i];
        bf16x4 v = base[(long)s * 64 + lane];
        a0 += w * (float)v[0]; a1 += w * (float)v[1];
        a2 += w * (float)v[2]; a3 += w * (float)v[3];
    }
    float4 b = ((const float4*)b1)[lane];
    bf16x4 o;
    o[0] = (__bf16)fmaxf(a0 + b.x, 0.f);
    o[1] = (__bf16)fmaxf(a1 + b.y, 0.f);
    o[2] = (__bf16)fmaxf(a2 + b.z, 0.f);
    o[3] = (__bf16)fmaxf(a3 + b.w, 0.f);
    ((bf16x4*)hb)[(long)n * 64 + lane] = o;
}

// ---------------- GEMM2 (MFMA): HMb = bf16(hb @ [W_mu|W_lv])   [NN,256]@[256,128] ----------------
// BM=128, BN=128, BK=32. 4 waves in 2x2.
__global__ __launch_bounds__(256) void k_gemm2(const __bf16* __restrict__ hb,
                                               const __bf16* __restrict__ Wp,
                                               __bf16* __restrict__ HMb) {
    __shared__ __bf16 As[128 * PAD];
    int tid = threadIdx.x;
    int wv = tid >> 6, lane = tid & 63;
    int quad = lane >> 4, l16 = lane & 15;
    int wr = (wv >> 1) * 64, wc = (wv & 1) * 64;
    long m0 = (long)blockIdx.x * 128;

    int srow = tid >> 1;            // 0..127
    int scol = (tid & 1) * 16;      // 0,16
    long grow = m0 + srow; if (grow > NN - 1) grow = NN - 1;
    const __bf16* hrow = hb + grow * NH;

    f32x4 acc[4][4];
#pragma unroll
    for (int a = 0; a < 4; a++)
#pragma unroll
        for (int b = 0; b < 4; b++) acc[a][b] = (f32x4)0.f;

    bf16x8 p0 = *(const bf16x8*)(hrow + scol);
    bf16x8 p1 = *(const bf16x8*)(hrow + scol + 8);

    for (int kc = 0; kc < 8; kc++) {
        *(bf16x8*)&As[srow * PAD + scol] = p0;
        *(bf16x8*)&As[srow * PAD + scol + 8] = p1;
        __syncthreads();
        if (kc < 7) {
            p0 = *(const bf16x8*)(hrow + (kc + 1) * 32 + scol);
            p1 = *(const bf16x8*)(hrow + (kc + 1) * 32 + scol + 8);
        }
        bf16x8 bfr[4];
#pragma unroll
        for (int nt = 0; nt < 4; nt++) {
            int ntg = (wc >> 4) + nt;
            bfr[nt] = *(const bf16x8*)(Wp + (((long)ntg * 8 + kc) * 64 + lane) * 8);
        }
#pragma unroll
        for (int mt = 0; mt < 4; mt++) {
            bf16x8 af = *(const bf16x8*)&As[(wr + mt * 16 + l16) * PAD + quad * 8];
#pragma unroll
            for (int nt = 0; nt < 4; nt++)
                acc[mt][nt] = __builtin_amdgcn_mfma_f32_16x16x32_bf16(af, bfr[nt], acc[mt][nt], 0, 0, 0);
        }
        __syncthreads();
    }
#pragma unroll
    for (int mt = 0; mt < 4; mt++)
#pragma unroll
        for (int r = 0; r < 4; r++) {
            long gr = m0 + wr + mt * 16 + quad * 4 + r;
            if (gr < NN) {
#pragma unroll
                for (int nt = 0; nt < 4; nt++)
                    HMb[gr * 128 + wc + nt * 16 + l16] = (__bf16)acc[mt][nt][r];
            }
        }
}

// ---------------- SpMM2 + bias: out = [adj@HM + b_mu ; adj@HL + b_lv] ----------------
__global__ __launch_bounds__(256) void k_spmm2(const __bf16* __restrict__ HMb,
                                               const int* __restrict__ ssrc,
                                               const float* __restrict__ sw,
                                               const int* __restrict__ row_ptr,
                                               const int* __restrict__ deg,
                                               const float* __restrict__ bmu,
                                               const float* __restrict__ blv,
                                               float* __restrict__ out) {
    int wave = threadIdx.x >> 6, lane = threadIdx.x & 63;
    int n = blockIdx.x * 4 + wave;
    if (n >= NN) return;
    int i = row_ptr[n];
    int end = i + deg[n];
    float a0 = 0.f, a1 = 0.f;
    const bf16x2* base = (const bf16x2*)HMb;  // row stride 64 bf16x2 (128 bf16)
    for (; i + 4 <= end; i += 4) {
        int s0 = ssrc[i], s1 = ssrc[i + 1], s2 = ssrc[i + 2], s3 = ssrc[i + 3];
        float w0 = sw[i], w1 = sw[i + 1], w2 = sw[i + 2], w3 = sw[i + 3];
        bf16x2 v0 = base[(long)s0 * 64 + lane];
        bf16x2 v1 = base[(long)s1 * 64 + lane];
        bf16x2 v2 = base[(long)s2 * 64 + lane];
        bf16x2 v3 = base[(long)s3 * 64 + lane];
        a0 += w0 * (float)v0[0] + w1 * (float)v1[0] + w2 * (float)v2[0] + w3 * (float)v3[0];
        a1 += w0 * (float)v0[1] + w1 * (float)v1[1] + w2 * (float)v2[1] + w3 * (float)v3[1];
    }
    for (; i < end; i++) {
        int s = ssrc[i];
        float w = sw[i];
        bf16x2 v = base[(long)s * 64 + lane];
        a0 += w * (float)v[0]; a1 += w * (float)v[1];
    }
    if (lane < 32) {  // cols 0..63 -> mu
        float2 b = ((const float2*)bmu)[lane];
        float2 o = {a0 + b.x, a1 + b.y};
        ((float2*)out)[(long)n * 32 + lane] = o;
    } else {          // cols 64..127 -> logvar
        float2 b = ((const float2*)blv)[lane - 32];
        float2 o = {a0 + b.x, a1 + b.y};
        ((float2*)(out + (long)NN * NL))[(long)n * 32 + (lane - 32)] = o;
    }
}

extern "C" void kernel_launch(void* const* d_in, const int* in_sizes, int n_in,
                              void* d_out, int out_size, void* d_ws, size_t ws_size,
                              hipStream_t stream) {
    const float* x   = (const float*)d_in[0];
    const int*   ei  = (const int*)d_in[1];
    const float* ew  = (const float*)d_in[2];
    const float* W1  = (const float*)d_in[3];
    const float* b1  = (const float*)d_in[4];
    const float* Wmu = (const float*)d_in[5];
    const float* bmu = (const float*)d_in[6];
    const float* Wlv = (const float*)d_in[7];
    const float* blv = (const float*)d_in[8];
    float* out = (float*)d_out;

    char* ws = (char*)d_ws;
    __bf16* XWb    = (__bf16*)(ws);                 // NN*256 bf16 (51.2 MB); reused as HMb (NN*128)
    __bf16* hb     = (__bf16*)(ws + 51200000);      // NN*256 bf16 (51.2 MB)
    int*   ssrc    = (int*)  (ws + 102400000);      // NE (12.8 MB)
    float* sw      = (float*)(ws + 115200000);      // NE (12.8 MB)
    int*   deg     = (int*)  (ws + 128000000);      // NN
    int*   row_ptr = (int*)  (ws + 128400000);      // NN
    int*   cursor  = (int*)  (ws + 128800000);      // NN
    int*   bsum    = (int*)  (ws + 129200000);      // NB_SCAN
    __bf16* Wp1    = (__bf16*)(ws + 129300000);     // 131072 bf16 (256 KB)
    __bf16* Wp2    = (__bf16*)(ws + 129600000);     // 32768 bf16 (64 KB)

    const int* esrc = ei;
    const int* edst = ei + NE;

    hipMemsetAsync(deg, 0, NN * sizeof(int), stream);
    hipMemsetAsync(cursor, 0, NN * sizeof(int), stream);

    // weight packing (L2-resident frag-order bf16)
    k_packW1<<<dim3(512), dim3(256), 0, stream>>>(W1, Wp1);
    k_packW2<<<dim3(128), dim3(256), 0, stream>>>(Wmu, Wlv, Wp2);

    // CSR build (sorted-by-dst edge list)
    k_hist<<<dim3((NE + 255) / 256), dim3(256), 0, stream>>>(edst, deg);
    k_blocksum<<<dim3(NB_SCAN), dim3(256), 0, stream>>>(deg, bsum);
    k_scan_partials<<<dim3(1), dim3(512), 0, stream>>>(bsum);
    k_scan_final<<<dim3(NB_SCAN), dim3(256), 0, stream>>>(deg, bsum, row_ptr);
    k_scatter<<<dim3((NE + 255) / 256), dim3(256), 0, stream>>>(esrc, edst, ew, row_ptr,
                                                                cursor, ssrc, sw);

    // layer 1
    k_gemm1<<<dim3((NN + 63) / 64), dim3(256), 0, stream>>>(x, Wp1, XWb);
    k_spmm1<<<dim3((NN + 3) / 4), dim3(256), 0, stream>>>(XWb, ssrc, sw, row_ptr, deg, b1, hb);

    // layer 2 (mu and logvar fused: 128-wide)
    k_gemm2<<<dim3((NN + 127) / 128), dim3(256), 0, stream>>>(hb, Wp2, XWb /* HMb */);
    k_spmm2<<<dim3((NN + 3) / 4), dim3(256), 0, stream>>>(XWb, ssrc, sw, row_ptr, deg, bmu, blv, out);
}

// Round 4
// 996.616 us; speedup vs baseline: 2.0440x; 1.0601x over previous
//
#include <hip/hip_runtime.h>
#include <hip/hip_bf16.h>

#define NN 100000
#define NE 3200000
#define NF 512
#define NH 256
#define NL 64
#define NB_SCAN 391   // ceil(NN/256)
#define PAD 40        // LDS row stride in bf16 elems

typedef __bf16 bf16x8 __attribute__((ext_vector_type(8)));
typedef __bf16 bf16x4 __attribute__((ext_vector_type(4)));
typedef __bf16 bf16x2 __attribute__((ext_vector_type(2)));
typedef float  f32x4  __attribute__((ext_vector_type(4)));

// ---------------- CSR build ----------------
__global__ void k_hist(const int* __restrict__ dst, int* __restrict__ deg) {
    int e = blockIdx.x * 256 + threadIdx.x;
    if (e < NE) atomicAdd(&deg[dst[e]], 1);
}

__global__ void k_blocksum(const int* __restrict__ deg, int* __restrict__ bsum) {
    __shared__ int s[256];
    int t = threadIdx.x;
    int i = blockIdx.x * 256 + t;
    s[t] = (i < NN) ? deg[i] : 0;
    __syncthreads();
    for (int off = 128; off > 0; off >>= 1) {
        if (t < off) s[t] += s[t + off];
        __syncthreads();
    }
    if (t == 0) bsum[blockIdx.x] = s[0];
}

__global__ void k_scan_partials(int* bsum) {
    __shared__ int s[512];
    int t = threadIdx.x;
    int v = (t < NB_SCAN) ? bsum[t] : 0;
    s[t] = v;
    __syncthreads();
    for (int off = 1; off < 512; off <<= 1) {
        int a = (t >= off) ? s[t - off] : 0;
        __syncthreads();
        s[t] += a;
        __syncthreads();
    }
    if (t < NB_SCAN) bsum[t] = s[t] - v;  // exclusive
}

__global__ void k_scan_final(const int* __restrict__ deg, const int* __restrict__ boff,
                             int* __restrict__ row_ptr) {
    __shared__ int s[2][256];
    int t = threadIdx.x;
    int i = blockIdx.x * 256 + t;
    int v = (i < NN) ? deg[i] : 0;
    int buf = 0;
    s[0][t] = v;
    __syncthreads();
    for (int off = 1; off < 256; off <<= 1) {
        int nv = s[buf][t] + ((t >= off) ? s[buf][t - off] : 0);
        buf ^= 1;
        s[buf][t] = nv;
        __syncthreads();
    }
    if (i < NN) row_ptr[i] = boff[blockIdx.x] + s[buf][t] - v;  // exclusive
}

__global__ void k_scatter(const int* __restrict__ src, const int* __restrict__ dst,
                          const float* __restrict__ w, const int* __restrict__ row_ptr,
                          int* __restrict__ cursor, int2* __restrict__ sedge) {
    int e = blockIdx.x * 256 + threadIdx.x;
    if (e < NE) {
        int d = dst[e];
        int p = row_ptr[d] + atomicAdd(&cursor[d], 1);
        sedge[p] = make_int2(src[e], (int)__float_as_uint(w[e]));
    }
}

// ---------------- weight packing into MFMA B-fragment order ----------------
__global__ void k_packW1(const float* __restrict__ W, __bf16* __restrict__ P) {
    int i = blockIdx.x * 256 + threadIdx.x;       // 131072 = 16nt * 16kc * 64 * 8
    int j = i & 7, l = (i >> 3) & 63, kc = (i >> 9) & 15, nt = i >> 13;
    int k = kc * 32 + (l >> 4) * 8 + j;
    int n = nt * 16 + (l & 15);
    P[i] = (__bf16)W[k * NH + n];
}

__global__ void k_packW2(const float* __restrict__ Wmu, const float* __restrict__ Wlv,
                         __bf16* __restrict__ P) {
    int i = blockIdx.x * 256 + threadIdx.x;       // 32768 = 8nt * 8kc * 64 * 8
    int j = i & 7, l = (i >> 3) & 63, kc = (i >> 9) & 7, nt = i >> 12;
    int k = kc * 32 + (l >> 4) * 8 + j;
    int n = nt * 16 + (l & 15);
    float v = (n < NL) ? Wmu[k * NL + n] : Wlv[k * NL + (n - NL)];
    P[i] = (__bf16)v;
}

// ---------------- GEMM1 (MFMA): XW split into two column-half tables ----------------
// BM=64, BN=256, BK=32. wave wv -> cols [wv*64, wv*64+64); wv 0,1 -> TA, wv 2,3 -> TB.
__global__ __launch_bounds__(256) void k_gemm1(const float* __restrict__ x,
                                               const __bf16* __restrict__ Wp,
                                               __bf16* __restrict__ TA,
                                               __bf16* __restrict__ TB) {
    __shared__ __bf16 As[64 * PAD];
    int tid = threadIdx.x;
    int wv = tid >> 6, lane = tid & 63;
    int quad = lane >> 4, l16 = lane & 15;
    long m0 = (long)blockIdx.x * 64;

    int srow = tid >> 2;            // 0..63
    int scol = (tid & 3) * 8;       // 0,8,16,24
    long grow = m0 + srow; if (grow > NN - 1) grow = NN - 1;
    const float* xrow = x + grow * NF;

    f32x4 acc[4][4];
#pragma unroll
    for (int a = 0; a < 4; a++)
#pragma unroll
        for (int b = 0; b < 4; b++) acc[a][b] = (f32x4)0.f;

    float4 p0 = *(const float4*)(xrow + scol);
    float4 p1 = *(const float4*)(xrow + scol + 4);

    for (int kc = 0; kc < 16; kc++) {
        union { bf16x8 v; __bf16 e[8]; } u;
        u.e[0] = (__bf16)p0.x; u.e[1] = (__bf16)p0.y;
        u.e[2] = (__bf16)p0.z; u.e[3] = (__bf16)p0.w;
        u.e[4] = (__bf16)p1.x; u.e[5] = (__bf16)p1.y;
        u.e[6] = (__bf16)p1.z; u.e[7] = (__bf16)p1.w;
        *(bf16x8*)&As[srow * PAD + scol] = u.v;
        __syncthreads();
        if (kc < 15) {
            p0 = *(const float4*)(xrow + (kc + 1) * 32 + scol);
            p1 = *(const float4*)(xrow + (kc + 1) * 32 + scol + 4);
        }
        bf16x8 bfr[4];
#pragma unroll
        for (int nt = 0; nt < 4; nt++)
            bfr[nt] = *(const bf16x8*)(Wp + (((long)(wv * 4 + nt) * 16 + kc) * 64 + lane) * 8);
#pragma unroll
        for (int mt = 0; mt < 4; mt++) {
            bf16x8 af = *(const bf16x8*)&As[(mt * 16 + l16) * PAD + quad * 8];
#pragma unroll
            for (int nt = 0; nt < 4; nt++)
                acc[mt][nt] = __builtin_amdgcn_mfma_f32_16x16x32_bf16(af, bfr[nt], acc[mt][nt], 0, 0, 0);
        }
        __syncthreads();
    }
    __bf16* T = (wv < 2) ? TA : TB;
    int c0 = (wv & 1) * 64;
#pragma unroll
    for (int mt = 0; mt < 4; mt++)
#pragma unroll
        for (int r = 0; r < 4; r++) {
            long gr = m0 + mt * 16 + quad * 4 + r;
            if (gr < NN) {
#pragma unroll
                for (int nt = 0; nt < 4; nt++)
                    T[gr * 128 + c0 + nt * 16 + l16] = (__bf16)acc[mt][nt][r];
            }
        }
}

// ---------------- SpMM half (layer 1): o = bf16(relu(adj @ T + bias)), 128-wide ----------------
__global__ __launch_bounds__(256) void k_spmm_h(const __bf16* __restrict__ T,
                                                const int2* __restrict__ sedge,
                                                const int* __restrict__ row_ptr,
                                                const int* __restrict__ deg,
                                                const float* __restrict__ bias,
                                                __bf16* __restrict__ o) {
    int wave = threadIdx.x >> 6, lane = threadIdx.x & 63;
    int n = blockIdx.x * 4 + wave;
    if (n >= NN) return;
    int i = row_ptr[n];
    int end = i + deg[n];
    float a0 = 0.f, a1 = 0.f;
    const bf16x2* base = (const bf16x2*)T;  // row stride 64 bf16x2
    for (; i + 8 <= end; i += 8) {
        int2 e0 = sedge[i], e1 = sedge[i+1], e2 = sedge[i+2], e3 = sedge[i+3];
        int2 e4 = sedge[i+4], e5 = sedge[i+5], e6 = sedge[i+6], e7 = sedge[i+7];
        bf16x2 v0 = base[(long)e0.x * 64 + lane];
        bf16x2 v1 = base[(long)e1.x * 64 + lane];
        bf16x2 v2 = base[(long)e2.x * 64 + lane];
        bf16x2 v3 = base[(long)e3.x * 64 + lane];
        bf16x2 v4 = base[(long)e4.x * 64 + lane];
        bf16x2 v5 = base[(long)e5.x * 64 + lane];
        bf16x2 v6 = base[(long)e6.x * 64 + lane];
        bf16x2 v7 = base[(long)e7.x * 64 + lane];
        a0 += __uint_as_float(e0.y) * (float)v0[0] + __uint_as_float(e1.y) * (float)v1[0]
            + __uint_as_float(e2.y) * (float)v2[0] + __uint_as_float(e3.y) * (float)v3[0]
            + __uint_as_float(e4.y) * (float)v4[0] + __uint_as_float(e5.y) * (float)v5[0]
            + __uint_as_float(e6.y) * (float)v6[0] + __uint_as_float(e7.y) * (float)v7[0];
        a1 += __uint_as_float(e0.y) * (float)v0[1] + __uint_as_float(e1.y) * (float)v1[1]
            + __uint_as_float(e2.y) * (float)v2[1] + __uint_as_float(e3.y) * (float)v3[1]
            + __uint_as_float(e4.y) * (float)v4[1] + __uint_as_float(e5.y) * (float)v5[1]
            + __uint_as_float(e6.y) * (float)v6[1] + __uint_as_float(e7.y) * (float)v7[1];
    }
    for (; i < end; i++) {
        int2 e = sedge[i];
        float w = __uint_as_float(e.y);
        bf16x2 v = base[(long)e.x * 64 + lane];
        a0 += w * (float)v[0]; a1 += w * (float)v[1];
    }
    float2 b = ((const float2*)bias)[lane];
    bf16x2 ov;
    ov[0] = (__bf16)fmaxf(a0 + b.x, 0.f);
    ov[1] = (__bf16)fmaxf(a1 + b.y, 0.f);
    ((bf16x2*)o)[(long)n * 64 + lane] = ov;
}

// ---------------- GEMM2 (MFMA): HMb = bf16(h @ [W_mu|W_lv]), h stored as two halves ----------------
// BM=128, BN=128, BK=32. 4 waves in 2x2.
__global__ __launch_bounds__(256) void k_gemm2(const __bf16* __restrict__ hA,
                                               const __bf16* __restrict__ hB,
                                               const __bf16* __restrict__ Wp,
                                               __bf16* __restrict__ HMb) {
    __shared__ __bf16 As[128 * PAD];
    int tid = threadIdx.x;
    int wv = tid >> 6, lane = tid & 63;
    int quad = lane >> 4, l16 = lane & 15;
    int wr = (wv >> 1) * 64, wc = (wv & 1) * 64;
    long m0 = (long)blockIdx.x * 128;

    int srow = tid >> 1;            // 0..127
    int scol = (tid & 1) * 16;      // 0,16
    long grow = m0 + srow; if (grow > NN - 1) grow = NN - 1;

    f32x4 acc[4][4];
#pragma unroll
    for (int a = 0; a < 4; a++)
#pragma unroll
        for (int b = 0; b < 4; b++) acc[a][b] = (f32x4)0.f;

    // k slice for kc: kc<4 -> hA cols kc*32.., kc>=4 -> hB cols (kc-4)*32..
    const __bf16* rA = hA + grow * 128;
    const __bf16* rB = hB + grow * 128;
    bf16x8 p0 = *(const bf16x8*)(rA + scol);
    bf16x8 p1 = *(const bf16x8*)(rA + scol + 8);

    for (int kc = 0; kc < 8; kc++) {
        *(bf16x8*)&As[srow * PAD + scol] = p0;
        *(bf16x8*)&As[srow * PAD + scol + 8] = p1;
        __syncthreads();
        if (kc < 7) {
            const __bf16* nxt = ((kc + 1) < 4 ? rA : rB) + ((kc + 1) & 3) * 32;
            p0 = *(const bf16x8*)(nxt + scol);
            p1 = *(const bf16x8*)(nxt + scol + 8);
        }
        bf16x8 bfr[4];
#pragma unroll
        for (int nt = 0; nt < 4; nt++) {
            int ntg = (wc >> 4) + nt;
            bfr[nt] = *(const bf16x8*)(Wp + (((long)ntg * 8 + kc) * 64 + lane) * 8);
        }
#pragma unroll
        for (int mt = 0; mt < 4; mt++) {
            bf16x8 af = *(const bf16x8*)&As[(wr + mt * 16 + l16) * PAD + quad * 8];
#pragma unroll
            for (int nt = 0; nt < 4; nt++)
                acc[mt][nt] = __builtin_amdgcn_mfma_f32_16x16x32_bf16(af, bfr[nt], acc[mt][nt], 0, 0, 0);
        }
        __syncthreads();
    }
#pragma unroll
    for (int mt = 0; mt < 4; mt++)
#pragma unroll
        for (int r = 0; r < 4; r++) {
            long gr = m0 + wr + mt * 16 + quad * 4 + r;
            if (gr < NN) {
#pragma unroll
                for (int nt = 0; nt < 4; nt++)
                    HMb[gr * 128 + wc + nt * 16 + l16] = (__bf16)acc[mt][nt][r];
            }
        }
}

// ---------------- SpMM2 + bias: out = [adj@HM + b_mu ; adj@HL + b_lv] ----------------
__global__ __launch_bounds__(256) void k_spmm2(const __bf16* __restrict__ HMb,
                                               const int2* __restrict__ sedge,
                                               const int* __restrict__ row_ptr,
                                               const int* __restrict__ deg,
                                               const float* __restrict__ bmu,
                                               const float* __restrict__ blv,
                                               float* __restrict__ out) {
    int wave = threadIdx.x >> 6, lane = threadIdx.x & 63;
    int n = blockIdx.x * 4 + wave;
    if (n >= NN) return;
    int i = row_ptr[n];
    int end = i + deg[n];
    float a0 = 0.f, a1 = 0.f;
    const bf16x2* base = (const bf16x2*)HMb;  // row stride 64 bf16x2
    for (; i + 8 <= end; i += 8) {
        int2 e0 = sedge[i], e1 = sedge[i+1], e2 = sedge[i+2], e3 = sedge[i+3];
        int2 e4 = sedge[i+4], e5 = sedge[i+5], e6 = sedge[i+6], e7 = sedge[i+7];
        bf16x2 v0 = base[(long)e0.x * 64 + lane];
        bf16x2 v1 = base[(long)e1.x * 64 + lane];
        bf16x2 v2 = base[(long)e2.x * 64 + lane];
        bf16x2 v3 = base[(long)e3.x * 64 + lane];
        bf16x2 v4 = base[(long)e4.x * 64 + lane];
        bf16x2 v5 = base[(long)e5.x * 64 + lane];
        bf16x2 v6 = base[(long)e6.x * 64 + lane];
        bf16x2 v7 = base[(long)e7.x * 64 + lane];
        a0 += __uint_as_float(e0.y) * (float)v0[0] + __uint_as_float(e1.y) * (float)v1[0]
            + __uint_as_float(e2.y) * (float)v2[0] + __uint_as_float(e3.y) * (float)v3[0]
            + __uint_as_float(e4.y) * (float)v4[0] + __uint_as_float(e5.y) * (float)v5[0]
            + __uint_as_float(e6.y) * (float)v6[0] + __uint_as_float(e7.y) * (float)v7[0];
        a1 += __uint_as_float(e0.y) * (float)v0[1] + __uint_as_float(e1.y) * (float)v1[1]
            + __uint_as_float(e2.y) * (float)v2[1] + __uint_as_float(e3.y) * (float)v3[1]
            + __uint_as_float(e4.y) * (float)v4[1] + __uint_as_float(e5.y) * (float)v5[1]
            + __uint_as_float(e6.y) * (float)v6[1] + __uint_as_float(e7.y) * (float)v7[1];
    }
    for (; i < end; i++) {
        int2 e = sedge[i];
        float w = __uint_as_float(e.y);
        bf16x2 v = base[(long)e.x * 64 + lane];
        a0 += w * (float)v[0]; a1 += w * (float)v[1];
    }
    if (lane < 32) {  // cols 0..63 -> mu
        float2 b = ((const float2*)bmu)[lane];
        float2 o = {a0 + b.x, a1 + b.y};
        ((float2*)out)[(long)n * 32 + lane] = o;
    } else {          // cols 64..127 -> logvar
        float2 b = ((const float2*)blv)[lane - 32];
        float2 o = {a0 + b.x, a1 + b.y};
        ((float2*)(out + (long)NN * NL))[(long)n * 32 + (lane - 32)] = o;
    }
}

extern "C" void kernel_launch(void* const* d_in, const int* in_sizes, int n_in,
                              void* d_out, int out_size, void* d_ws, size_t ws_size,
                              hipStream_t stream) {
    const float* x   = (const float*)d_in[0];
    const int*   ei  = (const int*)d_in[1];
    const float* ew  = (const float*)d_in[2];
    const float* W1  = (const float*)d_in[3];
    const float* b1  = (const float*)d_in[4];
    const float* Wmu = (const float*)d_in[5];
    const float* bmu = (const float*)d_in[6];
    const float* Wlv = (const float*)d_in[7];
    const float* blv = (const float*)d_in[8];
    float* out = (float*)d_out;

    char* ws = (char*)d_ws;
    __bf16* XWa    = (__bf16*)(ws);                  // NN*128 bf16 (25.6 MB)
    __bf16* XWb2   = (__bf16*)(ws + 25600000);       // NN*128 bf16
    __bf16* hA     = (__bf16*)(ws + 51200000);       // NN*128 bf16
    __bf16* hB     = (__bf16*)(ws + 76800000);       // NN*128 bf16
    __bf16* HMb    = (__bf16*)(ws + 102400000);      // NN*128 bf16
    int2*  sedge   = (int2*) (ws + 128000000);       // NE * 8 B (25.6 MB)
    int*   deg     = (int*)  (ws + 153600000);       // NN
    int*   row_ptr = (int*)  (ws + 154000000);       // NN
    int*   cursor  = (int*)  (ws + 154400000);       // NN
    int*   bsum    = (int*)  (ws + 154800000);       // NB_SCAN
    __bf16* Wp1    = (__bf16*)(ws + 154900000);      // 131072 bf16
    __bf16* Wp2    = (__bf16*)(ws + 155200000);      // 32768 bf16

    const int* esrc = ei;
    const int* edst = ei + NE;

    hipMemsetAsync(deg, 0, NN * sizeof(int), stream);
    hipMemsetAsync(cursor, 0, NN * sizeof(int), stream);

    // weight packing
    k_packW1<<<dim3(512), dim3(256), 0, stream>>>(W1, Wp1);
    k_packW2<<<dim3(128), dim3(256), 0, stream>>>(Wmu, Wlv, Wp2);

    // CSR build (sorted-by-dst edge list, payload packed int2)
    k_hist<<<dim3((NE + 255) / 256), dim3(256), 0, stream>>>(edst, deg);
    k_blocksum<<<dim3(NB_SCAN), dim3(256), 0, stream>>>(deg, bsum);
    k_scan_partials<<<dim3(1), dim3(512), 0, stream>>>(bsum);
    k_scan_final<<<dim3(NB_SCAN), dim3(256), 0, stream>>>(deg, bsum, row_ptr);
    k_scatter<<<dim3((NE + 255) / 256), dim3(256), 0, stream>>>(esrc, edst, ew, row_ptr,
                                                                cursor, sedge);

    // layer 1
    k_gemm1<<<dim3((NN + 63) / 64), dim3(256), 0, stream>>>(x, Wp1, XWa, XWb2);
    k_spmm_h<<<dim3((NN + 3) / 4), dim3(256), 0, stream>>>(XWa, sedge, row_ptr, deg, b1, hA);
    k_spmm_h<<<dim3((NN + 3) / 4), dim3(256), 0, stream>>>(XWb2, sedge, row_ptr, deg, b1 + 128, hB);

    // layer 2
    k_gemm2<<<dim3((NN + 127) / 128), dim3(256), 0, stream>>>(hA, hB, Wp2, HMb);
    k_spmm2<<<dim3((NN + 3) / 4), dim3(256), 0, stream>>>(HMb, sedge, row_ptr, deg, bmu, blv, out);
}